// Round 10
// baseline (1327.476 us; speedup 1.0000x reference)
//
#include <hip/hip_runtime.h>
#include <math.h>

#define NNODES  131072
#define NEDGES  393216

// ---------------- workspace layout (float offsets) ----------------
static const size_t OFF_X     = 0;                        // [N,128] = 16,777,216
static const size_t OFF_U     = 16777216;                 // 17,305,600 (PR1/pool1 alias; U uses first 16.7M)
static const size_t OFF_PA    = OFF_U + 16777216;         // 524,288 in U-region slack (PR1 dead by then)
static const size_t OFF_GPOOL = OFF_PA;                   // 4,096 (PA dead by pooling time)
static const size_t OFF_V     = OFF_U + 17305600;         // 16,777,216 (PR2 alias, then gemm V)
static const size_t OFF_AEXP  = OFF_V + 16777216;         // E*2 = 786,432 (raw logits)
static const size_t OFF_CUR   = OFF_AEXP + 786432;        // 131,072 ints
static const size_t OFF_CSRE  = OFF_CUR + 131072;         // E ints = 393,216
static const size_t OFF_WUV   = OFF_CSRE + 393216;        // 32,768
static const size_t OFF_UB    = OFF_WUV + 32768;          // 128
static const size_t OFF_STATS = OFF_UB + 128;             // 64 doubles = 128 floats
static const size_t OFF_SS    = OFF_STATS + 128;          // 64
static const size_t OFF_AMAX  = OFF_SS + 64;              // 4
// X-region transient aliases (all dead before bn_relu2 writes X):
//   PART  = X + 0          (<= 9248*64 = 591,872 floats)
//   W1T   = X + 1,000,000  (864)
//   W2T   = X + 1,001,000  (9,216)

__device__ inline unsigned enc_f(float f) {
  int b = __float_as_int(f);
  unsigned u = (unsigned)b;
  return (b >= 0) ? (u | 0x80000000u) : ~u;
}
__device__ inline float dec_f(unsigned e) {
  unsigned b = (e & 0x80000000u) ? (e & 0x7FFFFFFFu) : ~e;
  return __int_as_float((int)b);
}

// ---------------- weight repack ----------------
__global__ void repackW1_k(const float* __restrict__ W1, float* __restrict__ W1T) {
  int i = blockIdx.x * 256 + threadIdx.x;      // 864 = 27*32
  if (i >= 864) return;
  int j = i >> 5, c = i & 31;
  W1T[i] = W1[c * 27 + j];                     // W1T[j][cout]
}

__global__ void repackW2_k(const float* __restrict__ W2, float* __restrict__ W2T) {
  int i = blockIdx.x * 256 + threadIdx.x;      // 9216 = 288*32
  if (i >= 9216) return;
  int j = i >> 5, c = i & 31;
  W2T[i] = W2[c * 288 + j];                    // W2T[ci*9+k][cout]
}

// ---------------- conv block 1: LDS-tiled conv + raw maxpool + stat partials ----------------
// grid (17,17,32); pooled tile 8x8; pool1 stored CHANNEL-LAST [b][130*130][32] (RAW, BN applied by conv2 stage)
__global__ __launch_bounds__(256) void conv1_tiled_k(const float* __restrict__ x,
    const float* __restrict__ W1T, const float* __restrict__ b1,
    float* __restrict__ PR1, float* __restrict__ part) {
  __shared__ float in_t[972];                  // [ci][row*18+col], 3*18*18
  __shared__ float rs1[256], rs2[256];
  int tx = blockIdx.x, ty = blockIdx.y, b = blockIdx.z;
  int tid = threadIdx.x;
  int r0 = 16 * ty, c0 = 16 * tx;
  for (int idx = tid; idx < 972; idx += 256) {
    int ci = idx / 324, rc = idx - ci * 324;
    int row = rc / 18, col = rc - row * 18;
    int gr = r0 + row, gc = c0 + col;
    float v = 0.f;
    if (gr < 262 && gc < 262) v = x[(size_t)(b * 3 + ci) * 68644 + gr * 262 + gc];
    in_t[idx] = v;
  }
  __syncthreads();
  int c = tid & 31, pg = tid >> 5;
  float w[27];
#pragma unroll
  for (int j = 0; j < 27; ++j) w[j] = W1T[j * 32 + c];
  float bias = b1[c];
  int px = tx * 8 + pg;
  float s1 = 0.f, s2 = 0.f;
#pragma unroll
  for (int r = 0; r < 8; ++r) {
    int py = ty * 8 + r;
    if (py < 130 && px < 130) {
      float a00 = bias, a01 = bias, a10 = bias, a11 = bias;
#pragma unroll
      for (int ci = 0; ci < 3; ++ci) {
        const float* ip = &in_t[ci * 324 + (2 * r) * 18 + 2 * pg];
#pragma unroll
        for (int dy = 0; dy < 3; ++dy) {
#pragma unroll
          for (int dx = 0; dx < 3; ++dx) {
            float wv = w[ci * 9 + dy * 3 + dx];
            a00 += ip[dy * 18 + dx]           * wv;
            a01 += ip[dy * 18 + dx + 1]       * wv;
            a10 += ip[(dy + 1) * 18 + dx]     * wv;
            a11 += ip[(dy + 1) * 18 + dx + 1] * wv;
          }
        }
      }
      s1 += a00 + a01 + a10 + a11;
      s2 += a00 * a00 + a01 * a01 + a10 * a10 + a11 * a11;
      float m = fmaxf(fmaxf(a00, a01), fmaxf(a10, a11));
      PR1[((size_t)b * 16900 + py * 130 + px) * 32 + c] = m;
    }
  }
  rs1[tid] = s1; rs2[tid] = s2;
  __syncthreads();
  if (tid < 32) {
    float a = 0.f, q = 0.f;
    for (int g = 0; g < 8; ++g) { a += rs1[g * 32 + tid]; q += rs2[g * 32 + tid]; }
    int bid = (b * 17 + ty) * 17 + tx;
    part[(size_t)bid * 64 + tid * 2 + 0] = a;
    part[(size_t)bid * 64 + tid * 2 + 1] = q;
  }
}

__global__ void stats_reduce_k(const float* __restrict__ part, double* __restrict__ stats, int nb) {
  __shared__ double sd[256];
  int cnt = blockIdx.x;               // 0..63
  double s = 0.0;
  for (int b = threadIdx.x; b < nb; b += 256) s += (double)part[(size_t)b * 64 + cnt];
  sd[threadIdx.x] = s;
  __syncthreads();
  for (int o = 128; o > 0; o >>= 1) { if (threadIdx.x < o) sd[threadIdx.x] += sd[threadIdx.x + o]; __syncthreads(); }
  if (threadIdx.x == 0) stats[cnt] = sd[0];
}

__global__ void bn_finalize_k(const double* __restrict__ stats, const float* __restrict__ g,
                              const float* __restrict__ be, float* __restrict__ ss, double inv_cnt) {
  int c = threadIdx.x;
  if (c < 32) {
    double mu  = stats[c * 2 + 0] * inv_cnt;
    double var = stats[c * 2 + 1] * inv_cnt - mu * mu;
    double scale = (double)g[c] / sqrt(var + 1e-5);
    ss[c]      = (float)scale;
    ss[32 + c] = (float)((double)be[c] - mu * scale);
  }
}

// ---------------- conv block 2: LDS-tiled conv, ci-SPLIT (2 phases x 16 ci) ----------------
// grid (8,8,32); pooled tile 8x8 (64x64 exact); pool1 RAW channel-last in, PR2 channel-last out
// LDS halved (23 KB total) -> ~6 blocks/CU occupancy (was 3 at 44 KB).
__global__ __launch_bounds__(256) void conv2_tiled_k(const float* __restrict__ pool1,
    const float* __restrict__ ss, const float* __restrict__ W2T, const float* __restrict__ b2,
    float* __restrict__ PR2, float* __restrict__ part) {
  __shared__ float in_t[5184];                 // [(row*18+col)*16 + ci16], one 16-ci phase
  __shared__ float rs1[256], rs2[256];
  __shared__ float ssl[64];
  int tx = blockIdx.x, ty = blockIdx.y, b = blockIdx.z;
  int tid = threadIdx.x;
  if (tid < 64) ssl[tid] = ss[tid];
  int r0 = 16 * ty, c0 = 16 * tx;
  const float* pb = pool1 + ((size_t)b * 16900 + r0 * 130 + c0) * 32;
  int c = tid & 31, pg = tid >> 5;
  float bias = b2[c];
  float acc[8][4];
#pragma unroll
  for (int r = 0; r < 8; ++r) { acc[r][0] = bias; acc[r][1] = bias; acc[r][2] = bias; acc[r][3] = bias; }
  int cb = 2 * pg;                             // local conv col base
#pragma unroll 1
  for (int ph = 0; ph < 2; ++ph) {
    __syncthreads();                           // in_t (re)use safe; also covers ssl on ph=0
    int cib = ph * 16;
    for (int idx = tid; idx < 5184; idx += 256) {
      int rc = idx >> 4, ci16 = idx & 15;
      int row = rc / 18, col = rc - row * 18;
      int ci = cib + ci16;
      float v = pb[(size_t)(row * 130 + col) * 32 + ci];
      in_t[idx] = fmaxf(v * ssl[ci] + ssl[32 + ci], 0.f);   // fused BN1 + relu
    }
    __syncthreads();
#pragma unroll 1
    for (int ci16 = 0; ci16 < 16; ++ci16) {
      int ci = cib + ci16;
      float w[9];
#pragma unroll
      for (int k = 0; k < 9; ++k) w[k] = W2T[(ci * 9 + k) * 32 + c];
      float r0v[4], r1v[4], r2v[4], r3v[4];
#pragma unroll
      for (int q = 0; q < 4; ++q) {
        r0v[q] = in_t[(0 * 18 + cb + q) * 16 + ci16];
        r1v[q] = in_t[(1 * 18 + cb + q) * 16 + ci16];
      }
#pragma unroll
      for (int r = 0; r < 8; ++r) {
#pragma unroll
        for (int q = 0; q < 4; ++q) {
          r2v[q] = in_t[((2 * r + 2) * 18 + cb + q) * 16 + ci16];
          r3v[q] = in_t[((2 * r + 3) * 18 + cb + q) * 16 + ci16];
        }
#pragma unroll
        for (int dx = 0; dx < 3; ++dx) {
          float w0 = w[dx], w1 = w[3 + dx], w2 = w[6 + dx];
          acc[r][0] += r0v[dx]     * w0 + r1v[dx]     * w1 + r2v[dx]     * w2;
          acc[r][1] += r0v[dx + 1] * w0 + r1v[dx + 1] * w1 + r2v[dx + 1] * w2;
          acc[r][2] += r1v[dx]     * w0 + r2v[dx]     * w1 + r3v[dx]     * w2;
          acc[r][3] += r1v[dx + 1] * w0 + r2v[dx + 1] * w1 + r3v[dx + 1] * w2;
        }
#pragma unroll
        for (int q = 0; q < 4; ++q) { r0v[q] = r2v[q]; r1v[q] = r3v[q]; }
      }
    }
  }
  float s1 = 0.f, s2 = 0.f;
  int px = tx * 8 + pg;
#pragma unroll
  for (int r = 0; r < 8; ++r) {
    s1 += acc[r][0] + acc[r][1] + acc[r][2] + acc[r][3];
    s2 += acc[r][0] * acc[r][0] + acc[r][1] * acc[r][1] + acc[r][2] * acc[r][2] + acc[r][3] * acc[r][3];
    int py = ty * 8 + r;
    float m = fmaxf(fmaxf(acc[r][0], acc[r][1]), fmaxf(acc[r][2], acc[r][3]));
    PR2[((size_t)b * 4096 + py * 64 + px) * 32 + c] = m;
  }
  rs1[tid] = s1; rs2[tid] = s2;
  __syncthreads();
  if (tid < 32) {
    float a = 0.f, q = 0.f;
    for (int g = 0; g < 8; ++g) { a += rs1[g * 32 + tid]; q += rs2[g * 32 + tid]; }
    int bid = (b * 8 + ty) * 8 + tx;
    part[(size_t)bid * 64 + tid * 2 + 0] = a;
    part[(size_t)bid * 64 + tid * 2 + 1] = q;
  }
}

__global__ void bn_relu2_k(const float* __restrict__ PR2, const float* __restrict__ ss,
                           float* __restrict__ X) {
  int i = blockIdx.x * 256 + threadIdx.x;      // 4,194,304; channel-last
  int c = i & 31;
  X[i] = fmaxf(PR2[i] * ss[c] + ss[32 + c], 0.f);
}

// ---------------- CSR build (tgt-sorted incoming edge lists) ----------------
__global__ void deg_k(const int* __restrict__ tgt, int* __restrict__ cur) {
  int e = blockIdx.x * 256 + threadIdx.x;
  atomicAdd(&cur[tgt[e]], 1);
}

__global__ void scan_k(int* __restrict__ cur) {       // 1 block, 1024 threads, 131072 entries
  __shared__ int ls[1024];
  int tid = threadIdx.x;
  int base = tid * 128;
  int sum = 0;
  for (int i = 0; i < 128; ++i) sum += cur[base + i];
  ls[tid] = sum;
  __syncthreads();
  for (int off = 1; off < 1024; off <<= 1) {
    int v = (tid >= off) ? ls[tid - off] : 0;
    __syncthreads();
    ls[tid] += v;
    __syncthreads();
  }
  int excl = ls[tid] - sum;
  for (int i = 0; i < 128; ++i) { int d = cur[base + i]; cur[base + i] = excl; excl += d; }
}

__global__ void scatter_k(const int* __restrict__ tgt, int* __restrict__ cur,
                          int* __restrict__ csre) {
  int e = blockIdx.x * 256 + threadIdx.x;
  int t = tgt[e];
  int pos = atomicAdd(&cur[t], 1);
  csre[pos] = e;                       // store edge id; src/logits fetched via eo in gather
}
// after scatter: cur[t] == rowptr[t+1]; start(t) = (t==0)?0:cur[t-1]

// ---------------- GAT layer kernels ----------------
__global__ void repack2_k(const float* __restrict__ fW, const float* __restrict__ fb,
                          float* __restrict__ WUV, float* __restrict__ UB,
                          unsigned* __restrict__ amax, int D, int HF) {
  int NN = 2 * HF, D2 = 2 * D;
  int i = blockIdx.x * 256 + threadIdx.x;
  if (i < 2) amax[i] = 0x007FFFFFu;        // enc(-inf)
  if (i < HF) UB[i] = fb[i];
  if (i >= D * NN) return;
  int k = i / NN, j = i - k * NN;
  int half = (j >= HF) ? 1 : 0;
  int cc = j - half * HF;
  WUV[i] = fW[(size_t)cc * D2 + half * D + k];
}

// C[N x 2HF] = X[N x D] @ WUV[D x 2HF]; 128x64 tile, 8x4 acc/thread, BK=16
__global__ __launch_bounds__(256) void gemm_uv_k(const float* __restrict__ X,
    const float* __restrict__ WUV, const float* __restrict__ UB,
    float* __restrict__ U, float* __restrict__ V, int D, int HF) {
  const int NN = 2 * HF;
  __shared__ float As[16][132];  // [k][m], +4 pad
  __shared__ float Bs[16][68];   // [k][n]
  int tid = threadIdx.x;
  int tx = tid & 15, ty = tid >> 4;        // n = tx*4, m = ty*8
  int rm = blockIdx.y * 128;
  int cn = blockIdx.x * 64;
  float acc[8][4] = {};
  int ar = tid >> 1;             // 0..127 row
  int ak = (tid & 1) * 8;        // 0 or 8
  int bk = tid >> 4;             // 0..15
  int bj = (tid & 15) * 4;
  for (int kb = 0; kb < D; kb += 16) {
    const float* xr = &X[(size_t)(rm + ar) * D + kb + ak];
    float4 a0 = *(const float4*)&xr[0];
    float4 a1 = *(const float4*)&xr[4];
    float4 bv = *(const float4*)&WUV[(size_t)(kb + bk) * NN + cn + bj];
    __syncthreads();
    As[ak + 0][ar] = a0.x; As[ak + 1][ar] = a0.y; As[ak + 2][ar] = a0.z; As[ak + 3][ar] = a0.w;
    As[ak + 4][ar] = a1.x; As[ak + 5][ar] = a1.y; As[ak + 6][ar] = a1.z; As[ak + 7][ar] = a1.w;
    *(float4*)&Bs[bk][bj] = bv;
    __syncthreads();
#pragma unroll
    for (int k = 0; k < 16; ++k) {
      float4 am0 = *(float4*)&As[k][ty * 8];
      float4 am1 = *(float4*)&As[k][ty * 8 + 4];
      float4 b = *(float4*)&Bs[k][tx * 4];
      acc[0][0] += am0.x * b.x; acc[0][1] += am0.x * b.y; acc[0][2] += am0.x * b.z; acc[0][3] += am0.x * b.w;
      acc[1][0] += am0.y * b.x; acc[1][1] += am0.y * b.y; acc[1][2] += am0.y * b.z; acc[1][3] += am0.y * b.w;
      acc[2][0] += am0.z * b.x; acc[2][1] += am0.z * b.y; acc[2][2] += am0.z * b.z; acc[2][3] += am0.z * b.w;
      acc[3][0] += am0.w * b.x; acc[3][1] += am0.w * b.y; acc[3][2] += am0.w * b.z; acc[3][3] += am0.w * b.w;
      acc[4][0] += am1.x * b.x; acc[4][1] += am1.x * b.y; acc[4][2] += am1.x * b.z; acc[4][3] += am1.x * b.w;
      acc[5][0] += am1.y * b.x; acc[5][1] += am1.y * b.y; acc[5][2] += am1.y * b.z; acc[5][3] += am1.y * b.w;
      acc[6][0] += am1.z * b.x; acc[6][1] += am1.z * b.y; acc[6][2] += am1.z * b.z; acc[6][3] += am1.z * b.w;
      acc[7][0] += am1.w * b.x; acc[7][1] += am1.w * b.y; acc[7][2] += am1.w * b.z; acc[7][3] += am1.w * b.w;
    }
  }
  bool isU = (cn < HF);
  float4 ub = make_float4(0.f, 0.f, 0.f, 0.f);
  if (isU) ub = *(const float4*)&UB[cn + tx * 4];
  float* dstBase = isU ? (U + cn) : (V + (cn - HF));
#pragma unroll
  for (int i = 0; i < 8; ++i) {
    int row = rm + ty * 8 + i;
    float4 o = make_float4(acc[i][0] + ub.x, acc[i][1] + ub.y, acc[i][2] + ub.z, acc[i][3] + ub.w);
    *(float4*)&dstBase[(size_t)row * HF + tx * 4] = o;
  }
}

// per-node attention dots: PA[n] = {pu0+wb0, pu1+wb1, pv0, pv1}
__global__ void pvec_k(const float* __restrict__ X, const float* __restrict__ wW,
                       const float* __restrict__ wb, float* __restrict__ PA, int D) {
  __shared__ float PWs[4 * 132];
  int tid = threadIdx.x;              // 64
  int D2 = 2 * D;
  for (int i = tid; i < 4 * D; i += 64) {
    int v = i / D, k = i - v * D;
    PWs[v * 132 + k] = (v < 2) ? wW[v * D2 + k] : wW[(v - 2) * D2 + D + k];
  }
  __syncthreads();
  int v = tid & 3;
  int n = blockIdx.x * 16 + (tid >> 2);
  const float* xr = X + (size_t)n * D;
  float acc = 0.f;
  for (int k = 0; k < D; k += 4) {
    float4 xv = *(const float4*)&xr[k];
    acc += xv.x * PWs[v * 132 + k] + xv.y * PWs[v * 132 + k + 1]
         + xv.z * PWs[v * 132 + k + 2] + xv.w * PWs[v * 132 + k + 3];
  }
  if (v < 2) acc += wb[v];
  PA[(size_t)n * 4 + v] = acc;
}

// writes RAW logits to aexp; global max to amax (exact, monotone-encoded)
__global__ void edge_logit_k(const int* __restrict__ src, const int* __restrict__ tgt,
                             const float* __restrict__ PA, float* __restrict__ aexp,
                             unsigned* __restrict__ amax) {
  int e = blockIdx.x * 256 + threadIdx.x;
  int s = src[e], t = tgt[e];
  float4 ps = *(const float4*)&PA[(size_t)s * 4];
  float4 pt = *(const float4*)&PA[(size_t)t * 4];
  float a0 = ps.x + pt.z;
  float a1 = ps.y + pt.w;
  aexp[e * 2 + 0] = a0;
  aexp[e * 2 + 1] = a1;
#pragma unroll
  for (int o = 32; o > 0; o >>= 1) {
    a0 = fmaxf(a0, __shfl_down(a0, o));
    a1 = fmaxf(a1, __shfl_down(a1, o));
  }
  if ((threadIdx.x & 63) == 0) {
    atomicMax(&amax[0], enc_f(a0));
    atomicMax(&amax[1], enc_f(a1));
  }
}

// fused: exp(raw - max) + denominator + numerator + normalize; thread = (node, 4-channel group)
__global__ void gather_k(const int* __restrict__ cur, const int* __restrict__ csre,
                         const int* __restrict__ src, const float* __restrict__ aexp,
                         const unsigned* __restrict__ amax,
                         const float* __restrict__ U, const float* __restrict__ V,
                         float* __restrict__ X, int HF, int F, int lq) {
  int tid = blockIdx.x * 256 + threadIdx.x;
  int r4 = tid & ((HF >> 2) - 1);
  int t = tid >> lq;
  int r0 = r4 << 2;
  int h = (r0 >= F) ? 1 : 0;
  float mh = dec_f(amax[h]);
  int start = (t == 0) ? 0 : cur[t - 1];
  int end = cur[t];
  float4 v4 = *(const float4*)&V[(size_t)t * HF + r0];
  float ax = 0.f, ay = 0.f, az = 0.f, aw = 0.f, den = 0.f;
  for (int e = start; e < end; ++e) {
    int eo = csre[e];
    int s = src[eo];
    float ae = __expf(aexp[(size_t)eo * 2 + h] - mh);
    den += ae;
    const float4 u4 = *(const float4*)&U[(size_t)s * HF + r0];
    ax += ae * fmaxf(u4.x + v4.x, 0.f);
    ay += ae * fmaxf(u4.y + v4.y, 0.f);
    az += ae * fmaxf(u4.z + v4.z, 0.f);
    aw += ae * fmaxf(u4.w + v4.w, 0.f);
  }
  float inv = 1.f / (den + 1e-6f);
  float4 o = make_float4(ax * inv, ay * inv, az * inv, aw * inv);
  *(float4*)&X[(size_t)t * HF + r0] = o;
}

// ---------------- pooling + MLP head ----------------
__global__ void graph_pool_k(const float* __restrict__ X, float* __restrict__ gp) {
  int g = blockIdx.y, chunk = blockIdx.x, j = threadIdx.x;   // 128 threads
  int base = g * 4096 + chunk * 128;
  float acc = 0.f;
  for (int i = 0; i < 128; ++i) acc += X[(size_t)(base + i) * 128 + j];
  atomicAdd(&gp[g * 128 + j], acc);
}

__global__ void mlp_k(const float* __restrict__ gp, const float* __restrict__ m1W,
                      const float* __restrict__ m1b, const float* __restrict__ m2W,
                      const float* __restrict__ m2b, float* __restrict__ out) {
  __shared__ float hid[1024];
  int tid = threadIdx.x;                       // 1024 threads
  int g = tid >> 5, j = tid & 31;
  float acc = m1b[j];
  for (int k = 0; k < 128; ++k) acc += gp[g * 128 + k] * m1W[j * 128 + k];
  hid[g * 32 + j] = fmaxf(acc, 0.f);
  __syncthreads();
  if (tid < 320) {
    int gg = tid / 10, c2 = tid - gg * 10;
    float o = m2b[c2];
    for (int k = 0; k < 32; ++k) o += hid[gg * 32 + k] * m2W[c2 * 32 + k];
    out[gg * 10 + c2] = o;
  }
}

// ---------------- driver ----------------
extern "C" void kernel_launch(void* const* d_in, const int* in_sizes, int n_in,
                              void* d_out, int out_size, void* d_ws, size_t ws_size,
                              hipStream_t stream) {
  (void)in_sizes; (void)n_in; (void)out_size; (void)ws_size;
  const float* x   = (const float*)d_in[0];
  const float* W1  = (const float*)d_in[1];
  const float* b1  = (const float*)d_in[2];
  const float* g1  = (const float*)d_in[3];
  const float* be1 = (const float*)d_in[4];
  const float* W2  = (const float*)d_in[5];
  const float* b2  = (const float*)d_in[6];
  const float* g2  = (const float*)d_in[7];
  const float* be2 = (const float*)d_in[8];
  const int* src = (const int*)d_in[25];
  const int* tgt = (const int*)d_in[26];

  float* ws = (float*)d_ws;
  float* X     = ws + OFF_X;
  float* PR1   = ws + OFF_U;        // conv1 pooled-raw (channel-last); BN1 applied in conv2 stage
  float* U     = ws + OFF_U;        // gemm U output (PR1 dead by then)
  float* V     = ws + OFF_V;        // PR2 alias, then gemm V output
  float* AEXP  = ws + OFF_AEXP;     // raw logits
  float* PA    = ws + OFF_PA;       // in U-region slack beyond U's N*HF use
  int*   CUR   = (int*)(ws + OFF_CUR);
  int*   CSRE  = (int*)(ws + OFF_CSRE);
  float* WUV   = ws + OFF_WUV;
  float* UB    = ws + OFF_UB;
  double* STATS= (double*)(ws + OFF_STATS);
  float* SS    = ws + OFF_SS;
  float* GPOOL = ws + OFF_GPOOL;    // aliases dead PA at the end
  unsigned* AMAX = (unsigned*)(ws + OFF_AMAX);
  float* PART  = X;                 // conv stat partials; dead before bn_relu2
  float* W1T   = X + 1000000;       // repacked weights; dead before bn_relu2
  float* W2T   = X + 1001000;

  // weight repack
  repackW1_k<<<4, 256, 0, stream>>>(W1, W1T);
  repackW2_k<<<36, 256, 0, stream>>>(W2, W2T);

  // conv block 1: LDS-tiled conv pass (raw pooled out) + stat partials, reduce -> SS (BN1)
  conv1_tiled_k<<<dim3(17, 17, 32), 256, 0, stream>>>(x, W1T, b1, PR1, PART);
  stats_reduce_k<<<64, 256, 0, stream>>>(PART, STATS, 9248);
  bn_finalize_k<<<1, 64, 0, stream>>>(STATS, g1, be1, SS, 1.0 / 2163200.0);   // 32*260*260

  // conv block 2: BN1+relu fused into stage; ci-split phases; BN2+relu -> X[N,32]
  conv2_tiled_k<<<dim3(8, 8, 32), 256, 0, stream>>>(PR1, SS, W2T, b2, V, PART);
  stats_reduce_k<<<64, 256, 0, stream>>>(PART, STATS, 2048);
  bn_finalize_k<<<1, 64, 0, stream>>>(STATS, g2, be2, SS, 1.0 / 524288.0);    // 32*128*128
  bn_relu2_k<<<16384, 256, 0, stream>>>(V, SS, X);

  // CSR build (tgt-major incoming lists)
  hipMemsetAsync(CUR, 0, NNODES * sizeof(int), stream);
  deg_k<<<NEDGES / 256, 256, 0, stream>>>(tgt, CUR);
  scan_k<<<1, 1024, 0, stream>>>(CUR);
  scatter_k<<<NEDGES / 256, 256, 0, stream>>>(tgt, CUR, CSRE);

  // three GAT layers (X in-place across layers)
  for (int l = 0; l < 3; ++l) {
    int D  = (l == 0) ? 32 : (l == 1) ? 64 : 128;
    int F  = (l == 0) ? 32 : 64;
    int HF = 2 * F, NN = 2 * HF;
    int lq = (l == 0) ? 4 : 5;       // log2(HF/4)
    const float* fW = (const float*)d_in[9  + l * 4];
    const float* fb = (const float*)d_in[10 + l * 4];
    const float* wW = (const float*)d_in[11 + l * 4];
    const float* wb = (const float*)d_in[12 + l * 4];

    repack2_k<<<(D * NN + 255) / 256, 256, 0, stream>>>(fW, fb, WUV, UB, AMAX, D, HF);
    gemm_uv_k<<<dim3(NN / 64, NNODES / 128), 256, 0, stream>>>(X, WUV, UB, U, V, D, HF);
    pvec_k<<<NNODES / 16, 64, 0, stream>>>(X, wW, wb, PA, D);
    edge_logit_k<<<NEDGES / 256, 256, 0, stream>>>(src, tgt, PA, AEXP, AMAX);
    gather_k<<<(NNODES * (HF / 4)) / 256, 256, 0, stream>>>(CUR, CSRE, src, AEXP, AMAX, U, V, X, HF, F, lq);
  }

  // graph sum-pool + MLP head
  hipMemsetAsync(GPOOL, 0, 4096 * sizeof(float), stream);
  graph_pool_k<<<dim3(32, 32), 128, 0, stream>>>(X, GPOOL);
  mlp_k<<<1, 1024, 0, stream>>>(GPOOL, (const float*)d_in[21], (const float*)d_in[22],
                                (const float*)d_in[23], (const float*)d_in[24], (float*)d_out);
}